// Round 17
// baseline (221.016 us; speedup 1.0000x reference)
//
#include <hip/hip_runtime.h>
#include <math.h>

// TransformerBlock for MI355X — FINAL (round-21 config, best measured 219.1us).
// Session trajectory 255.6 -> 219.1 (-14.3%). Key wins: attn deep pipeline
// (counted vmcnt, V dbuf, K triple-buffer cover 2.0, ONE barrier/iter),
// defer-rescale softmax (__expf; exp2f/ocml is a trap), cvt_pkrtz P stores,
// q fp16 pre-scaled, XCD-chunked swizzles (KV FETCH 74->12MB), GEMM
// triple-buffer + vmcnt(4), fast tanh-GELU (erff libcall deleted, -8.5us).
// Measured-negative: BN=64 tiles, 64-row attn q-tiles, attn occupancy boost.

#define TOKENS 8192
#define SEQ    2048
typedef unsigned short u16;
typedef __attribute__((ext_vector_type(8))) _Float16 h8;
typedef __attribute__((ext_vector_type(4))) float f32x4;
typedef __attribute__((ext_vector_type(4))) unsigned short u16x4;

__device__ __forceinline__ u16 f2h(float f) {
    _Float16 h = (_Float16)f;               // v_cvt_f16_f32, RTNE
    return __builtin_bit_cast(u16, h);
}
__device__ __forceinline__ unsigned int pk2h(float a, float b) {
    // v_cvt_pkrtz_f16_f32: two f32 -> packed 2x fp16 (RTZ), one instr.
    return __builtin_bit_cast(unsigned int, __builtin_amdgcn_cvt_pkrtz(a, b));
}
__device__ __forceinline__ void a16(void* lds, const void* g) {
    __builtin_amdgcn_global_load_lds(
        (const __attribute__((address_space(1))) unsigned int*)g,
        (__attribute__((address_space(3))) unsigned int*)lds, 16, 0, 0);
}
__device__ __forceinline__ float gelu_fast(float x) {
    // 0.5x(1+tanh(0.79788456(x+0.044715x^3))) == x*e/(e+1),
    // e = exp(1.59576912x + 0.07135481x^3). Max abs err ~1e-3.
    const float t = x * x;
    const float e = __expf(x * (1.5957691216f + 0.0713548163f * t));
    return x * e * __builtin_amdgcn_rcpf(e + 1.0f);
}

// ---------------------------------------------------------------------------
// prep: blocks 0..511 = weight transpose -> fp16 [N][K]; 512..2559 = LN1 -> fp16.
// LN1 rows XCD-aligned (g=(f&7)*256+f/8).
// ---------------------------------------------------------------------------
__global__ __launch_bounds__(256) void prep_k(const float* __restrict__ wqkv,
                                              const float* __restrict__ wout,
                                              const float* __restrict__ w1,
                                              const float* __restrict__ w2,
                                              u16* __restrict__ dqkv,
                                              u16* __restrict__ dout,
                                              u16* __restrict__ d1,
                                              u16* __restrict__ d2,
                                              const float* __restrict__ x,
                                              const float* __restrict__ g,
                                              const float* __restrict__ bta,
                                              u16* __restrict__ oh) {
    const int tid = threadIdx.x;
    if (blockIdx.x >= 512) {
        const int f = blockIdx.x - 512;
        const int grp = ((f & 7) << 8) | (f >> 3);   // XCD-aligned row group
        const int lane = tid & 63;
        const int row  = (grp << 2) + (tid >> 6);
        const float* xr = x + ((size_t)row << 9) + (lane << 3);
        float v[8];
        *(float4*)&v[0] = *(const float4*)xr;
        *(float4*)&v[4] = *(const float4*)(xr + 4);
        float s = 0.f, ss = 0.f;
#pragma unroll
        for (int i = 0; i < 8; i++) { s += v[i]; ss += v[i] * v[i]; }
#pragma unroll
        for (int m = 32; m; m >>= 1) {
            s  += __shfl_xor(s, m, 64);
            ss += __shfl_xor(ss, m, 64);
        }
        const float mu   = s * (1.0f / 512.0f);
        const float rstd = rsqrtf(ss * (1.0f / 512.0f) - mu * mu + 1e-5f);
        float gg[8], bb[8];
        *(float4*)&gg[0] = *(const float4*)(g + (lane << 3));
        *(float4*)&gg[4] = *(const float4*)(g + (lane << 3) + 4);
        *(float4*)&bb[0] = *(const float4*)(bta + (lane << 3));
        *(float4*)&bb[4] = *(const float4*)(bta + (lane << 3) + 4);
        union { u16 us[8]; uint4 q; } H;
#pragma unroll
        for (int i = 0; i < 8; i++) H.us[i] = f2h((v[i] - mu) * rstd * gg[i] + bb[i]);
        *(uint4*)&oh[((size_t)row << 9) + (lane << 3)] = H.q;
        return;
    }
    __shared__ float t[64][65];
    int b = blockIdx.x;
    const float* src; u16* dst; int K, N, n0, k0;
    if (b < 192)      { src = wqkv; dst = dqkv; K = 512;  N = 1536; n0 = (b % 24) << 6; k0 = (b / 24) << 6; }
    else if (b < 256) { b -= 192; src = wout; dst = dout; K = 512;  N = 512;  n0 = (b & 7) << 6;  k0 = (b >> 3) << 6; }
    else if (b < 384) { b -= 256; src = w1;   dst = d1;   K = 512;  N = 1024; n0 = (b & 15) << 6; k0 = (b >> 4) << 6; }
    else              { b -= 384; src = w2;   dst = d2;   K = 1024; N = 512;  n0 = (b & 7) << 6;  k0 = (b >> 3) << 6; }
    {
        const int kr = tid >> 2, nc = (tid & 3) << 4;
        const float* p = src + (size_t)(k0 + kr) * N + n0 + nc;
#pragma unroll
        for (int i = 0; i < 4; i++)
            *(float4*)&t[kr][nc + (i << 2)] = *(const float4*)(p + (i << 2));
    }
    __syncthreads();
    {
        const int nr = tid >> 2, kc = (tid & 3) << 4;
        union { u16 us[16]; uint4 q[2]; } H;
#pragma unroll
        for (int i = 0; i < 16; i++) H.us[i] = f2h(t[kc + i][nr]);
        const size_t o = (size_t)(n0 + nr) * K + k0 + kc;
        *(uint4*)&dst[o] = H.q[0];
        *(uint4*)&dst[o + 8] = H.q[1];
    }
}

// ---------------------------------------------------------------------------
// LayerNorm (LN2) -> fp16. XCD-aligned row groups.
// ---------------------------------------------------------------------------
__global__ __launch_bounds__(256) void ln_k(const float* __restrict__ x,
                                            const float* __restrict__ g,
                                            const float* __restrict__ bta,
                                            u16* __restrict__ oh) {
    const int B = blockIdx.x;
    const int grp = ((B & 7) << 8) | (B >> 3);
    const int lane = threadIdx.x & 63;
    const int row  = (grp << 2) + (threadIdx.x >> 6);
    const float* xr = x + ((size_t)row << 9) + (lane << 3);
    float v[8];
    *(float4*)&v[0] = *(const float4*)xr;
    *(float4*)&v[4] = *(const float4*)(xr + 4);
    float s = 0.f, ss = 0.f;
#pragma unroll
    for (int i = 0; i < 8; i++) { s += v[i]; ss += v[i] * v[i]; }
#pragma unroll
    for (int m = 32; m; m >>= 1) {
        s  += __shfl_xor(s, m, 64);
        ss += __shfl_xor(ss, m, 64);
    }
    const float mu   = s * (1.0f / 512.0f);
    const float rstd = rsqrtf(ss * (1.0f / 512.0f) - mu * mu + 1e-5f);
    float gg[8], bb[8];
    *(float4*)&gg[0] = *(const float4*)(g + (lane << 3));
    *(float4*)&gg[4] = *(const float4*)(g + (lane << 3) + 4);
    *(float4*)&bb[0] = *(const float4*)(bta + (lane << 3));
    *(float4*)&bb[4] = *(const float4*)(bta + (lane << 3) + 4);
    union { u16 us[8]; uint4 q; } H;
#pragma unroll
    for (int i = 0; i < 8; i++) H.us[i] = f2h((v[i] - mu) * rstd * gg[i] + bb[i]);
    *(uint4*)&oh[((size_t)row << 9) + (lane << 3)] = H.q;
}

// ---------------------------------------------------------------------------
// fp16 MFMA GEMM: C = A[M,K]B[K,N]; A fp16 [M][K], B fp16 [N][K].
// 128x128 tile, BK=32, 4 waves 2x2, triple-buffered staging (48KB LDS),
// counted vmcnt(4). XCD-chunked blockIdx swizzle.
// EPI 0: qkv scatter (q fp16 *0.125 | kh [bh][key][d] | vth via LDS transpose)
// EPI 1/3: +bias +res -> Cf f32     EPI 2: +bias, fast GELU -> Ch fp16
// ---------------------------------------------------------------------------
template <int EPI>
__global__ __launch_bounds__(256, 3) void sgemm_k(
    const u16* __restrict__ A, const u16* __restrict__ B,
    const float* __restrict__ bias, const float* __restrict__ res,
    float* __restrict__ Cf, u16* __restrict__ Ch, u16* __restrict__ Dh,
    int M, int N, int K) {
    __shared__ u16 sm[24576];
    const int tid = threadIdx.x;
    const int lane = tid & 63, wv = tid >> 6;
    const int col = lane & 15, quad = lane >> 4;
    const int wm = (wv & 1) << 6, wn = (wv >> 1) << 6;

    // XCD-chunked swizzle (grids are multiples of 8).
    const int nbx  = gridDim.x;
    const int flat = blockIdx.x + blockIdx.y * nbx;
    const int nwg  = nbx * gridDim.y;
    const int lid  = ((flat & 7) * (nwg >> 3)) + (flat >> 3);
    const int bm = (lid / nbx) << 7, bn = (lid % nbx) << 7;

    const int r0 = tid >> 2,         c0 = (tid & 3) ^ ((r0 >> 1) & 3);
    const int r1 = (tid + 256) >> 2, c1 = (tid & 3) ^ ((r1 >> 1) & 3);
    const u16* Ag0 = A + (size_t)(bm + r0) * K + c0 * 8;
    const u16* Ag1 = A + (size_t)(bm + r1) * K + c1 * 8;
    const u16* Bg0 = B + (size_t)(bn + r0) * K + c0 * 8;
    const u16* Bg1 = B + (size_t)(bn + r1) * K + c1 * 8;
    const int lw0 = wv * 512, lw1 = wv * 512 + 2048;
    const int swz = (col >> 1) & 3;
    const f32x4 z4 = {0.f, 0.f, 0.f, 0.f};
    f32x4 acc[4][4] = {{z4,z4,z4,z4},{z4,z4,z4,z4},{z4,z4,z4,z4},{z4,z4,z4,z4}};

    // prologue: stage tiles 0 and 1 into buffers 0 and 1 (8 loads/wave out)
    a16(&sm[lw0],        Ag0);       a16(&sm[lw1],        Ag1);
    a16(&sm[lw0 + 4096], Bg0);       a16(&sm[lw1 + 4096], Bg1);
    a16(&sm[8192 + lw0],        Ag0 + 32);  a16(&sm[8192 + lw1],        Ag1 + 32);
    a16(&sm[8192 + lw0 + 4096], Bg0 + 32);  a16(&sm[8192 + lw1 + 4096], Bg1 + 32);

    int cb = 0;      // buffer holding tile for this iteration
    int nb = 16384;  // buffer to receive tile k+2
    for (int k0 = 0; k0 < K; k0 += 32) {
        // retire only the tile we are about to read; keep next tile in flight.
        if (k0 + 32 < K) {
            asm volatile("s_waitcnt vmcnt(4) lgkmcnt(0)\n\ts_barrier" ::: "memory");
        } else {
            asm volatile("s_waitcnt vmcnt(0) lgkmcnt(0)\n\ts_barrier" ::: "memory");
        }
        if (k0 + 64 < K) {
            const int kn = k0 + 64;
            a16(&sm[nb + lw0],        Ag0 + kn);  a16(&sm[nb + lw1],        Ag1 + kn);
            a16(&sm[nb + lw0 + 4096], Bg0 + kn);  a16(&sm[nb + lw1 + 4096], Bg1 + kn);
        }
        h8 af[4];
#pragma unroll
        for (int mt = 0; mt < 4; mt++) {
            const int ra = cb + (wm + (mt << 4) + col) * 32 + ((quad ^ swz) << 3);
            af[mt] = *(const h8*)&sm[ra];
        }
#pragma unroll
        for (int nt = 0; nt < 4; nt++) {
            const int rb = cb + 4096 + (wn + (nt << 4) + col) * 32 + ((quad ^ swz) << 3);
            h8 bf = *(const h8*)&sm[rb];
#pragma unroll
            for (int mt = 0; mt < 4; mt++)
                acc[mt][nt] = __builtin_amdgcn_mfma_f32_16x16x32_f16(af[mt], bf, acc[mt][nt], 0, 0, 0);
        }
        nb = cb;
        cb = (cb == 16384) ? 0 : cb + 8192;
    }

    if constexpr (EPI == 0) {
        if (bn >= 1024) {
            // ---- V region: LDS transpose -> coalesced vth stores ----
            const int hd0  = (bn - 1024) >> 6;
            const int b8   = (bm >> 11) << 3;
            const int keyb = bm & 2047;
            __syncthreads();  // staging buffers done
#pragma unroll
            for (int hf = 0; hf < 2; hf++) {
                if ((wv >> 1) == hf) {
#pragma unroll
                    for (int mt = 0; mt < 4; mt++)
#pragma unroll
                    for (int rr = 0; rr < 4; rr++) {
                        const int key = wm + (mt << 4) + (quad << 2) + rr;
#pragma unroll
                        for (int nt = 0; nt < 4; nt++) {
                            const int dl = (nt << 4) + col;
                            sm[dl * 136 + key] = f2h(acc[mt][nt][rr]);
                        }
                    }
                }
                __syncthreads();
                {
                    const int d = tid >> 2;
#pragma unroll
                    for (int c = 0; c < 4; c++) {
                        const int key0 = ((((tid & 3) << 2) + c) << 3);
                        const size_t gb = ((size_t)(b8 + hd0 + hf) << 17)
                                        + ((size_t)d << 11) + keyb + key0;
                        *(uint4*)&Dh[gb] = *(const uint4*)&sm[d * 136 + key0];
                    }
                }
                __syncthreads();
            }
            return;
        }
    }

    float bs[4];
    if constexpr (EPI >= 1) {
#pragma unroll
        for (int nt = 0; nt < 4; nt++) bs[nt] = bias[bn + wn + (nt << 4) + col];
    }
#pragma unroll
    for (int mt = 0; mt < 4; mt++) {
#pragma unroll
        for (int rr = 0; rr < 4; rr++) {
            const int row = bm + wm + (mt << 4) + (quad << 2) + rr;
#pragma unroll
            for (int nt = 0; nt < 4; nt++) {
                const int colg = bn + wn + (nt << 4) + col;
                float v = acc[mt][nt][rr];
                if constexpr (EPI == 0) {
                    const int b = row >> 11, key = row & 2047;
                    if (bn < 512) {
                        // q: fp16 with softmax scale pre-folded.
                        ((u16*)Cf)[((size_t)row << 9) + colg] = f2h(v * 0.125f);
                    } else {
                        const int hd = (colg - 512) >> 6, d = colg & 63;
                        Ch[((size_t)((b << 3) + hd) << 17) + (key << 6) + d] = f2h(v);
                    }
                } else if constexpr (EPI == 2) {
                    Ch[(size_t)row * N + colg] = f2h(gelu_fast(v + bs[nt]));
                } else {
                    const size_t o = (size_t)row * N + colg;
                    Cf[o] = v + bs[nt] + res[o];
                }
            }
        }
    }
}

// ---------------------------------------------------------------------------
// Flash attention, fp16: 256-thr blocks, 4 waves x TWO 16-row q-subtiles.
// Grid (16,32)=512=2/CU (grid-limited -> 56KB LDS costs no occupancy).
// ONE barrier per iteration: per-wave vmcnt(2)+lgkm(0) before s_barrier
// retires exactly K[jt],V[jt] (K[jt+1] stays in flight); all staging
// (V[jt+1], K[jt+2]) issued after the barrier. K TRIPLE-buffered (cover
// 2.0 iters), V double-buffered. P wave-private (lgkm-only fence).
// defer-rescale THR=7.5 __expf, pkrtz P, setprio on MFMA, XCD swizzle.
// LDS 56KB (u16 idx): K 3x4096 [0,12288) | V 2x4096 [12288,20480) | P [20480,28672)
// ---------------------------------------------------------------------------
__global__ __launch_bounds__(256, 2) void attn_k(const u16* __restrict__ q,
                                                 const u16* __restrict__ kh,
                                                 const u16* __restrict__ vth,
                                                 u16* __restrict__ ah) {
    __shared__ u16 sm[28672];
    const int tid = threadIdx.x;
    const int lane = tid & 63, wv = tid >> 6;   // wv in {0..3}
    const int col = lane & 15, quad = lane >> 4;
    // XCD-chunked swizzle over flat grid 512: 4 consecutive bh per XCD.
    const int flat = blockIdx.x + (blockIdx.y << 4);
    const int lid  = ((flat & 7) << 6) + (flat >> 3);
    const int qt = lid & 15, bh = lid >> 4;
    const int b = bh >> 3, h = bh & 7;
    const size_t tok0 = (size_t)b * SEQ;
    const size_t bhK = (size_t)bh << 17;
    const int q0 = qt << 7;   // 128-row q tile

    // Q fragments: two 16-row subtiles per wave (B-operand; scale pre-folded).
    h8 qf[2][2];
#pragma unroll
    for (int sub = 0; sub < 2; sub++) {
        const int qrow = q0 + (wv << 5) + (sub << 4) + col;
        const u16* qp = q + ((tok0 + qrow) << 9) + (h << 6) + (quad << 3);
#pragma unroll
        for (int kc = 0; kc < 2; kc++)
            qf[sub][kc] = *(const h8*)(qp + (kc << 5));
    }

    const f32x4 z4 = {0.f, 0.f, 0.f, 0.f};
    f32x4 o[2][4] = {{z4, z4, z4, z4}, {z4, z4, z4, z4}};
    float m_run[2] = {-1e30f, -1e30f}, l_run[2] = {0.f, 0.f};

    // staging map: 512 chunks/tile; wave wv issue j covers chunk ((j*4+wv)*64+lane)
    size_t kbz[2], vbz[2];
    int doff[2];
#pragma unroll
    for (int j = 0; j < 2; j++) {
        const int C = (((j << 2) + wv) << 6) + lane;
        const int sr = C >> 3, sp = (C & 7) ^ (sr & 7);
        kbz[j] = bhK + ((size_t)sr << 6) + (sp << 3);   // + jt*4096
        vbz[j] = bhK + ((size_t)sr << 11) + (sp << 3);  // + jt*64
        doff[j] = (((j << 2) + wv) << 9);
    }

    // prologue: K[0]->Kb0, V[0]->Vb0, K[1]->Kb1  (6 loads/wave outstanding)
#pragma unroll
    for (int j = 0; j < 2; j++) a16(&sm[doff[j]], kh + kbz[j]);
#pragma unroll
    for (int j = 0; j < 2; j++) a16(&sm[12288 + doff[j]], vth + vbz[j]);
#pragma unroll
    for (int j = 0; j < 2; j++) a16(&sm[4096 + doff[j]], kh + kbz[j] + 4096);

    int kcur = 0;  // u16 base of Kb[jt%3]
    for (int jt = 0; jt < 32; jt++) {
        // ONE barrier: retire own K[jt],V[jt] chunks (K[jt+1] in flight),
        // then sync -> all waves' chunks complete, all prior LDS reads done.
        if (jt < 31) {
            asm volatile("s_waitcnt vmcnt(2) lgkmcnt(0)\n\ts_barrier" ::: "memory");
        } else {
            asm volatile("s_waitcnt vmcnt(0) lgkmcnt(0)\n\ts_barrier" ::: "memory");
        }
        // issue V[jt+1] (other V buffer) and K[jt+2] (free K buffer).
        if (jt < 31) {
            const size_t vo = (size_t)(jt + 1) << 6;
            const int vb = 12288 + (((jt + 1) & 1) << 12);
#pragma unroll
            for (int j = 0; j < 2; j++) a16(&sm[vb + doff[j]], vth + vbz[j] + vo);
        }
        if (jt < 30) {
            const size_t ko = (size_t)(jt + 2) << 12;
            int kt = kcur + 8192; if (kt >= 12288) kt -= 12288;
#pragma unroll
            for (int j = 0; j < 2; j++) a16(&sm[kt + doff[j]], kh + kbz[j] + ko);
        }

        // ---- St[key][q] = K · Qᵀ (K frags feed both subtiles) ----
        f32x4 st0[4] = {z4, z4, z4, z4}, st1[4] = {z4, z4, z4, z4};
        __builtin_amdgcn_s_setprio(1);
#pragma unroll
        for (int kb = 0; kb < 4; kb++) {
            const int key = (kb << 4) + col;
            const int r64 = key << 6, k7 = key & 7;
#pragma unroll
            for (int kc = 0; kc < 2; kc++) {
                const int ofs = kcur + r64 + ((((kc << 2) + quad) ^ k7) << 3);
                h8 kf = *(const h8*)&sm[ofs];
                st0[kb] = __builtin_amdgcn_mfma_f32_16x16x32_f16(kf, qf[0][kc], st0[kb], 0, 0, 0);
                st1[kb] = __builtin_amdgcn_mfma_f32_16x16x32_f16(kf, qf[1][kc], st1[kb], 0, 0, 0);
            }
        }
        __builtin_amdgcn_s_setprio(0);

        // ---- online softmax per subtile (defer-rescale, __expf, pkrtz) ----
#pragma unroll
        for (int sub = 0; sub < 2; sub++) {
            f32x4* st = sub ? st1 : st0;
            const int prow = (wv << 5) + (sub << 4) + col;
            const int p64 = prow << 6, p7 = prow & 7;
            float mx = st[0][0];
#pragma unroll
            for (int kb = 0; kb < 4; kb++)
#pragma unroll
                for (int r = 0; r < 4; r++) mx = fmaxf(mx, st[kb][r]);
            mx = fmaxf(mx, __shfl_xor(mx, 16));
            mx = fmaxf(mx, __shfl_xor(mx, 32));
            if (__any(mx > m_run[sub] + 7.5f)) {
                const float mn  = fmaxf(m_run[sub], mx);
                const float alp = __expf(m_run[sub] - mn);
                m_run[sub] = mn;
                l_run[sub] *= alp;
                float aO[4];
#pragma unroll
                for (int r = 0; r < 4; r++) aO[r] = __shfl(alp, (quad << 2) + r);
#pragma unroll
                for (int db = 0; db < 4; db++) {
                    o[sub][db][0] *= aO[0]; o[sub][db][1] *= aO[1];
                    o[sub][db][2] *= aO[2]; o[sub][db][3] *= aO[3];
                }
            }
            float p[16];
            float rs = 0.0f;
#pragma unroll
            for (int kb = 0; kb < 4; kb++)
#pragma unroll
                for (int r = 0; r < 4; r++) {
                    float e = __expf(st[kb][r] - m_run[sub]);   // bounded by e^7.5
                    p[(kb << 2) + r] = e;
                    rs += e;
                }
            rs += __shfl_xor(rs, 16);
            rs += __shfl_xor(rs, 32);
            l_run[sub] += rs;
#pragma unroll
            for (int kb = 0; kb < 4; kb++) {
                uint2 w;
                w.x = pk2h(p[(kb << 2) + 0], p[(kb << 2) + 1]);
                w.y = pk2h(p[(kb << 2) + 2], p[(kb << 2) + 3]);
                const int c = (kb << 1) + (quad >> 1);
                *(uint2*)&sm[20480 + p64 + ((c ^ p7) << 3) + ((quad & 1) << 2)] = w;
            }
        }

        // wave-local fence: own P writes visible to own P reads. No barrier.
        asm volatile("s_waitcnt lgkmcnt(0)" ::: "memory");

        h8 pf[2][2];
#pragma unroll
        for (int sub = 0; sub < 2; sub++) {
            const int prow = (wv << 5) + (sub << 4) + col;
            const int p64 = prow << 6, p7 = prow & 7;
#pragma unroll
            for (int kc = 0; kc < 2; kc++)
                pf[sub][kc] = *(const h8*)&sm[20480 + p64 + ((((kc << 2) + quad) ^ p7) << 3)];
        }

        // ---- O += P · V (V frags feed both subtiles) ----
        const int vbase = 12288 + ((jt & 1) << 12);
        __builtin_amdgcn_s_setprio(1);
#pragma unroll
        for (int db = 0; db < 4; db++) {
            const int d = (db << 4) + col;
            const int v64 = vbase + (d << 6), d7 = d & 7;
#pragma unroll
            for (int kc = 0; kc < 2; kc++) {
                h8 vf = *(const h8*)&sm[v64 + ((((kc << 2) + quad) ^ d7) << 3)];
                o[0][db] = __builtin_amdgcn_mfma_f32_16x16x32_f16(pf[0][kc], vf, o[0][db], 0, 0, 0);
                o[1][db] = __builtin_amdgcn_mfma_f32_16x16x32_f16(pf[1][kc], vf, o[1][db], 0, 0, 0);
            }
        }
        __builtin_amdgcn_s_setprio(0);

        kcur = (kcur == 8192) ? 0 : kcur + 4096;
    }

    // ---- epilogue: O/l -> fp16 attended [tok][h*64+d] ----
#pragma unroll
    for (int sub = 0; sub < 2; sub++) {
        float linv[4];
#pragma unroll
        for (int r = 0; r < 4; r++) linv[r] = 1.0f / __shfl(l_run[sub], (quad << 2) + r);
#pragma unroll
        for (int r = 0; r < 4; r++) {
            const size_t rowo = ((tok0 + q0 + (wv << 5) + (sub << 4) + (quad << 2) + r) << 9)
                                + (h << 6) + col;
#pragma unroll
            for (int db = 0; db < 4; db++)
                ah[rowo + (db << 4)] = f2h(o[sub][db][r] * linv[r]);
        }
    }
}

// ---------------------------------------------------------------------------
extern "C" void kernel_launch(void* const* d_in, const int* in_sizes, int n_in,
                              void* d_out, int out_size, void* d_ws, size_t ws_size,
                              hipStream_t stream) {
    const float* x     = (const float*)d_in[0];
    const float* ln1_g = (const float*)d_in[1];
    const float* ln1_b = (const float*)d_in[2];
    const float* w_qkv = (const float*)d_in[3];
    const float* w_out = (const float*)d_in[4];
    const float* b_out = (const float*)d_in[5];
    const float* ln2_g = (const float*)d_in[6];
    const float* ln2_b = (const float*)d_in[7];
    const float* w1    = (const float*)d_in[8];
    const float* b1    = (const float*)d_in[9];
    const float* w2    = (const float*)d_in[10];
    const float* b2    = (const float*)d_in[11];
    float* out = (float*)d_out;

    u16* wqkvh = (u16*)d_ws;                       // [1536][512] fp16
    u16* wouth = wqkvh + 1536 * 512;               // [512][512]
    u16* w1h   = wouth + 512 * 512;                // [1024][512]
    u16* w2h   = w1h + 1024 * 512;                 // [512][1024]
    u16* hbuf  = w2h + 512 * 1024;                 // [8192][512] fp16: h/att/mid
    float* qbuf = (float*)(hbuf + (size_t)TOKENS * 512);   // region: q fp16 / x2 f32
    u16* qh16   = (u16*)qbuf;                              // [8192][512] fp16 (q*0.125)
    float* x2   = qbuf;                                    // alias (after attn)
    u16* kh  = (u16*)(qbuf + (size_t)TOKENS * 512);        // [32][2048][64] fp16
    u16* vth = kh + (size_t)32 * 131072;                   // [32][64][2048] fp16
    u16* gh  = kh;                                         // [8192][1024] fp16 (aliases k+v)

    prep_k<<<2560, 256, 0, stream>>>(w_qkv, w_out, w1, w2, wqkvh, wouth, w1h, w2h,
                                     x, ln1_g, ln1_b, hbuf);
    sgemm_k<0><<<dim3(12, 64), 256, 0, stream>>>(hbuf, wqkvh, nullptr, nullptr,
                                                 (float*)qh16, kh, vth, TOKENS, 1536, 512);
    attn_k<<<dim3(16, 32), 256, 0, stream>>>(qh16, kh, vth, hbuf);
    sgemm_k<1><<<dim3(4, 64), 256, 0, stream>>>(hbuf, wouth, b_out, x,
                                                x2, nullptr, nullptr, TOKENS, 512, 512);
    ln_k<<<TOKENS / 4, 256, 0, stream>>>(x2, ln2_g, ln2_b, hbuf);
    sgemm_k<2><<<dim3(8, 64), 256, 0, stream>>>(hbuf, w1h, b1, nullptr,
                                                nullptr, gh, nullptr, TOKENS, 1024, 512);
    sgemm_k<3><<<dim3(4, 64), 256, 0, stream>>>(gh, w2h, b2, x2,
                                                out, nullptr, nullptr, TOKENS, 512, 1024);
}

// Round 18
// 218.123 us; speedup vs baseline: 1.0133x; 1.0133x over previous
//
#include <hip/hip_runtime.h>
#include <math.h>

// TransformerBlock for MI355X — round 23: fp16 residual stream.
// r21 config (best, 219-221us) + x2 stored fp16: sgemm<1> epilogue writes
// f2h(v+bias+res), ln_k reads fp16, sgemm<3> residual converts fp16->f32.
// Saves ~25MB of f32 traffic across 3 kernels. Risk: +~0.005 absmax from
// fp16 rounding of the residual (criterion: revert if absmax > ~0.06).

#define TOKENS 8192
#define SEQ    2048
typedef unsigned short u16;
typedef __attribute__((ext_vector_type(8))) _Float16 h8;
typedef __attribute__((ext_vector_type(4))) float f32x4;
typedef __attribute__((ext_vector_type(4))) unsigned short u16x4;

__device__ __forceinline__ u16 f2h(float f) {
    _Float16 h = (_Float16)f;               // v_cvt_f16_f32, RTNE
    return __builtin_bit_cast(u16, h);
}
__device__ __forceinline__ float h2f(u16 u) {
    return (float)__builtin_bit_cast(_Float16, u);
}
__device__ __forceinline__ unsigned int pk2h(float a, float b) {
    // v_cvt_pkrtz_f16_f32: two f32 -> packed 2x fp16 (RTZ), one instr.
    return __builtin_bit_cast(unsigned int, __builtin_amdgcn_cvt_pkrtz(a, b));
}
__device__ __forceinline__ void a16(void* lds, const void* g) {
    __builtin_amdgcn_global_load_lds(
        (const __attribute__((address_space(1))) unsigned int*)g,
        (__attribute__((address_space(3))) unsigned int*)lds, 16, 0, 0);
}
__device__ __forceinline__ float gelu_fast(float x) {
    // 0.5x(1+tanh(0.79788456(x+0.044715x^3))) == x*e/(e+1),
    // e = exp(1.59576912x + 0.07135481x^3). Max abs err ~1e-3.
    const float t = x * x;
    const float e = __expf(x * (1.5957691216f + 0.0713548163f * t));
    return x * e * __builtin_amdgcn_rcpf(e + 1.0f);
}

// ---------------------------------------------------------------------------
// prep: blocks 0..511 = weight transpose -> fp16 [N][K]; 512..2559 = LN1 -> fp16.
// LN1 rows XCD-aligned (g=(f&7)*256+f/8).
// ---------------------------------------------------------------------------
__global__ __launch_bounds__(256) void prep_k(const float* __restrict__ wqkv,
                                              const float* __restrict__ wout,
                                              const float* __restrict__ w1,
                                              const float* __restrict__ w2,
                                              u16* __restrict__ dqkv,
                                              u16* __restrict__ dout,
                                              u16* __restrict__ d1,
                                              u16* __restrict__ d2,
                                              const float* __restrict__ x,
                                              const float* __restrict__ g,
                                              const float* __restrict__ bta,
                                              u16* __restrict__ oh) {
    const int tid = threadIdx.x;
    if (blockIdx.x >= 512) {
        const int f = blockIdx.x - 512;
        const int grp = ((f & 7) << 8) | (f >> 3);   // XCD-aligned row group
        const int lane = tid & 63;
        const int row  = (grp << 2) + (tid >> 6);
        const float* xr = x + ((size_t)row << 9) + (lane << 3);
        float v[8];
        *(float4*)&v[0] = *(const float4*)xr;
        *(float4*)&v[4] = *(const float4*)(xr + 4);
        float s = 0.f, ss = 0.f;
#pragma unroll
        for (int i = 0; i < 8; i++) { s += v[i]; ss += v[i] * v[i]; }
#pragma unroll
        for (int m = 32; m; m >>= 1) {
            s  += __shfl_xor(s, m, 64);
            ss += __shfl_xor(ss, m, 64);
        }
        const float mu   = s * (1.0f / 512.0f);
        const float rstd = rsqrtf(ss * (1.0f / 512.0f) - mu * mu + 1e-5f);
        float gg[8], bb[8];
        *(float4*)&gg[0] = *(const float4*)(g + (lane << 3));
        *(float4*)&gg[4] = *(const float4*)(g + (lane << 3) + 4);
        *(float4*)&bb[0] = *(const float4*)(bta + (lane << 3));
        *(float4*)&bb[4] = *(const float4*)(bta + (lane << 3) + 4);
        union { u16 us[8]; uint4 q; } H;
#pragma unroll
        for (int i = 0; i < 8; i++) H.us[i] = f2h((v[i] - mu) * rstd * gg[i] + bb[i]);
        *(uint4*)&oh[((size_t)row << 9) + (lane << 3)] = H.q;
        return;
    }
    __shared__ float t[64][65];
    int b = blockIdx.x;
    const float* src; u16* dst; int K, N, n0, k0;
    if (b < 192)      { src = wqkv; dst = dqkv; K = 512;  N = 1536; n0 = (b % 24) << 6; k0 = (b / 24) << 6; }
    else if (b < 256) { b -= 192; src = wout; dst = dout; K = 512;  N = 512;  n0 = (b & 7) << 6;  k0 = (b >> 3) << 6; }
    else if (b < 384) { b -= 256; src = w1;   dst = d1;   K = 512;  N = 1024; n0 = (b & 15) << 6; k0 = (b >> 4) << 6; }
    else              { b -= 384; src = w2;   dst = d2;   K = 1024; N = 512;  n0 = (b & 7) << 6;  k0 = (b >> 3) << 6; }
    {
        const int kr = tid >> 2, nc = (tid & 3) << 4;
        const float* p = src + (size_t)(k0 + kr) * N + n0 + nc;
#pragma unroll
        for (int i = 0; i < 4; i++)
            *(float4*)&t[kr][nc + (i << 2)] = *(const float4*)(p + (i << 2));
    }
    __syncthreads();
    {
        const int nr = tid >> 2, kc = (tid & 3) << 4;
        union { u16 us[16]; uint4 q[2]; } H;
#pragma unroll
        for (int i = 0; i < 16; i++) H.us[i] = f2h(t[kc + i][nr]);
        const size_t o = (size_t)(n0 + nr) * K + k0 + kc;
        *(uint4*)&dst[o] = H.q[0];
        *(uint4*)&dst[o + 8] = H.q[1];
    }
}

// ---------------------------------------------------------------------------
// LayerNorm (LN2) -> fp16. Input x2 is fp16 (residual stream). XCD-aligned.
// ---------------------------------------------------------------------------
__global__ __launch_bounds__(256) void ln_k(const u16* __restrict__ x,
                                            const float* __restrict__ g,
                                            const float* __restrict__ bta,
                                            u16* __restrict__ oh) {
    const int B = blockIdx.x;
    const int grp = ((B & 7) << 8) | (B >> 3);
    const int lane = threadIdx.x & 63;
    const int row  = (grp << 2) + (threadIdx.x >> 6);
    const u16* xr = x + ((size_t)row << 9) + (lane << 3);
    union { u16 us[8]; uint4 q; } X;
    X.q = *(const uint4*)xr;
    float v[8];
#pragma unroll
    for (int i = 0; i < 8; i++) v[i] = h2f(X.us[i]);
    float s = 0.f, ss = 0.f;
#pragma unroll
    for (int i = 0; i < 8; i++) { s += v[i]; ss += v[i] * v[i]; }
#pragma unroll
    for (int m = 32; m; m >>= 1) {
        s  += __shfl_xor(s, m, 64);
        ss += __shfl_xor(ss, m, 64);
    }
    const float mu   = s * (1.0f / 512.0f);
    const float rstd = rsqrtf(ss * (1.0f / 512.0f) - mu * mu + 1e-5f);
    float gg[8], bb[8];
    *(float4*)&gg[0] = *(const float4*)(g + (lane << 3));
    *(float4*)&gg[4] = *(const float4*)(g + (lane << 3) + 4);
    *(float4*)&bb[0] = *(const float4*)(bta + (lane << 3));
    *(float4*)&bb[4] = *(const float4*)(bta + (lane << 3) + 4);
    union { u16 us[8]; uint4 q; } H;
#pragma unroll
    for (int i = 0; i < 8; i++) H.us[i] = f2h((v[i] - mu) * rstd * gg[i] + bb[i]);
    *(uint4*)&oh[((size_t)row << 9) + (lane << 3)] = H.q;
}

// ---------------------------------------------------------------------------
// fp16 MFMA GEMM: C = A[M,K]B[K,N]; A fp16 [M][K], B fp16 [N][K].
// 128x128 tile, BK=32, 4 waves 2x2, triple-buffered staging (48KB LDS),
// counted vmcnt(4). XCD-chunked blockIdx swizzle.
// EPI 0: qkv scatter (q fp16 *0.125 | kh | vth via LDS transpose)
// EPI 1: +bias +res(f32) -> Ch fp16 (residual stream x2)
// EPI 2: +bias, fast GELU -> Ch fp16
// EPI 3: +bias +res(fp16) -> Cf f32 (final output)
// ---------------------------------------------------------------------------
template <int EPI>
__global__ __launch_bounds__(256, 3) void sgemm_k(
    const u16* __restrict__ A, const u16* __restrict__ B,
    const float* __restrict__ bias, const float* __restrict__ res,
    float* __restrict__ Cf, u16* __restrict__ Ch, u16* __restrict__ Dh,
    int M, int N, int K) {
    __shared__ u16 sm[24576];
    const int tid = threadIdx.x;
    const int lane = tid & 63, wv = tid >> 6;
    const int col = lane & 15, quad = lane >> 4;
    const int wm = (wv & 1) << 6, wn = (wv >> 1) << 6;

    // XCD-chunked swizzle (grids are multiples of 8).
    const int nbx  = gridDim.x;
    const int flat = blockIdx.x + blockIdx.y * nbx;
    const int nwg  = nbx * gridDim.y;
    const int lid  = ((flat & 7) * (nwg >> 3)) + (flat >> 3);
    const int bm = (lid / nbx) << 7, bn = (lid % nbx) << 7;

    const int r0 = tid >> 2,         c0 = (tid & 3) ^ ((r0 >> 1) & 3);
    const int r1 = (tid + 256) >> 2, c1 = (tid & 3) ^ ((r1 >> 1) & 3);
    const u16* Ag0 = A + (size_t)(bm + r0) * K + c0 * 8;
    const u16* Ag1 = A + (size_t)(bm + r1) * K + c1 * 8;
    const u16* Bg0 = B + (size_t)(bn + r0) * K + c0 * 8;
    const u16* Bg1 = B + (size_t)(bn + r1) * K + c1 * 8;
    const int lw0 = wv * 512, lw1 = wv * 512 + 2048;
    const int swz = (col >> 1) & 3;
    const f32x4 z4 = {0.f, 0.f, 0.f, 0.f};
    f32x4 acc[4][4] = {{z4,z4,z4,z4},{z4,z4,z4,z4},{z4,z4,z4,z4},{z4,z4,z4,z4}};

    // prologue: stage tiles 0 and 1 into buffers 0 and 1 (8 loads/wave out)
    a16(&sm[lw0],        Ag0);       a16(&sm[lw1],        Ag1);
    a16(&sm[lw0 + 4096], Bg0);       a16(&sm[lw1 + 4096], Bg1);
    a16(&sm[8192 + lw0],        Ag0 + 32);  a16(&sm[8192 + lw1],        Ag1 + 32);
    a16(&sm[8192 + lw0 + 4096], Bg0 + 32);  a16(&sm[8192 + lw1 + 4096], Bg1 + 32);

    int cb = 0;      // buffer holding tile for this iteration
    int nb = 16384;  // buffer to receive tile k+2
    for (int k0 = 0; k0 < K; k0 += 32) {
        // retire only the tile we are about to read; keep next tile in flight.
        if (k0 + 32 < K) {
            asm volatile("s_waitcnt vmcnt(4) lgkmcnt(0)\n\ts_barrier" ::: "memory");
        } else {
            asm volatile("s_waitcnt vmcnt(0) lgkmcnt(0)\n\ts_barrier" ::: "memory");
        }
        if (k0 + 64 < K) {
            const int kn = k0 + 64;
            a16(&sm[nb + lw0],        Ag0 + kn);  a16(&sm[nb + lw1],        Ag1 + kn);
            a16(&sm[nb + lw0 + 4096], Bg0 + kn);  a16(&sm[nb + lw1 + 4096], Bg1 + kn);
        }
        h8 af[4];
#pragma unroll
        for (int mt = 0; mt < 4; mt++) {
            const int ra = cb + (wm + (mt << 4) + col) * 32 + ((quad ^ swz) << 3);
            af[mt] = *(const h8*)&sm[ra];
        }
#pragma unroll
        for (int nt = 0; nt < 4; nt++) {
            const int rb = cb + 4096 + (wn + (nt << 4) + col) * 32 + ((quad ^ swz) << 3);
            h8 bf = *(const h8*)&sm[rb];
#pragma unroll
            for (int mt = 0; mt < 4; mt++)
                acc[mt][nt] = __builtin_amdgcn_mfma_f32_16x16x32_f16(af[mt], bf, acc[mt][nt], 0, 0, 0);
        }
        nb = cb;
        cb = (cb == 16384) ? 0 : cb + 8192;
    }

    if constexpr (EPI == 0) {
        if (bn >= 1024) {
            // ---- V region: LDS transpose -> coalesced vth stores ----
            const int hd0  = (bn - 1024) >> 6;
            const int b8   = (bm >> 11) << 3;
            const int keyb = bm & 2047;
            __syncthreads();  // staging buffers done
#pragma unroll
            for (int hf = 0; hf < 2; hf++) {
                if ((wv >> 1) == hf) {
#pragma unroll
                    for (int mt = 0; mt < 4; mt++)
#pragma unroll
                    for (int rr = 0; rr < 4; rr++) {
                        const int key = wm + (mt << 4) + (quad << 2) + rr;
#pragma unroll
                        for (int nt = 0; nt < 4; nt++) {
                            const int dl = (nt << 4) + col;
                            sm[dl * 136 + key] = f2h(acc[mt][nt][rr]);
                        }
                    }
                }
                __syncthreads();
                {
                    const int d = tid >> 2;
#pragma unroll
                    for (int c = 0; c < 4; c++) {
                        const int key0 = ((((tid & 3) << 2) + c) << 3);
                        const size_t gb = ((size_t)(b8 + hd0 + hf) << 17)
                                        + ((size_t)d << 11) + keyb + key0;
                        *(uint4*)&Dh[gb] = *(const uint4*)&sm[d * 136 + key0];
                    }
                }
                __syncthreads();
            }
            return;
        }
    }

    float bs[4];
    if constexpr (EPI >= 1) {
#pragma unroll
        for (int nt = 0; nt < 4; nt++) bs[nt] = bias[bn + wn + (nt << 4) + col];
    }
#pragma unroll
    for (int mt = 0; mt < 4; mt++) {
#pragma unroll
        for (int rr = 0; rr < 4; rr++) {
            const int row = bm + wm + (mt << 4) + (quad << 2) + rr;
#pragma unroll
            for (int nt = 0; nt < 4; nt++) {
                const int colg = bn + wn + (nt << 4) + col;
                float v = acc[mt][nt][rr];
                if constexpr (EPI == 0) {
                    const int b = row >> 11, key = row & 2047;
                    if (bn < 512) {
                        // q: fp16 with softmax scale pre-folded.
                        ((u16*)Cf)[((size_t)row << 9) + colg] = f2h(v * 0.125f);
                    } else {
                        const int hd = (colg - 512) >> 6, d = colg & 63;
                        Ch[((size_t)((b << 3) + hd) << 17) + (key << 6) + d] = f2h(v);
                    }
                } else if constexpr (EPI == 1) {
                    // residual stream x2 stored fp16
                    const size_t o = (size_t)row * N + colg;
                    Ch[o] = f2h(v + bs[nt] + res[o]);
                } else if constexpr (EPI == 2) {
                    Ch[(size_t)row * N + colg] = f2h(gelu_fast(v + bs[nt]));
                } else {
                    // final: f32 out, fp16 residual
                    const size_t o = (size_t)row * N + colg;
                    Cf[o] = v + bs[nt] + h2f(((const u16*)res)[o]);
                }
            }
        }
    }
}

// ---------------------------------------------------------------------------
// Flash attention, fp16: 256-thr blocks, 4 waves x TWO 16-row q-subtiles.
// Grid (16,32)=512=2/CU. ONE barrier/iter (vmcnt(2)+lgkm), K triple-buffer
// (cover 2.0), V dbuf, P wave-private, defer-rescale THR=7.5 __expf,
// pkrtz P, setprio, XCD swizzle, q fp16 pre-scaled.
// LDS 56KB (u16 idx): K 3x4096 [0,12288) | V 2x4096 [12288,20480) | P [20480,28672)
// ---------------------------------------------------------------------------
__global__ __launch_bounds__(256, 2) void attn_k(const u16* __restrict__ q,
                                                 const u16* __restrict__ kh,
                                                 const u16* __restrict__ vth,
                                                 u16* __restrict__ ah) {
    __shared__ u16 sm[28672];
    const int tid = threadIdx.x;
    const int lane = tid & 63, wv = tid >> 6;   // wv in {0..3}
    const int col = lane & 15, quad = lane >> 4;
    // XCD-chunked swizzle over flat grid 512: 4 consecutive bh per XCD.
    const int flat = blockIdx.x + (blockIdx.y << 4);
    const int lid  = ((flat & 7) << 6) + (flat >> 3);
    const int qt = lid & 15, bh = lid >> 4;
    const int b = bh >> 3, h = bh & 7;
    const size_t tok0 = (size_t)b * SEQ;
    const size_t bhK = (size_t)bh << 17;
    const int q0 = qt << 7;   // 128-row q tile

    // Q fragments: two 16-row subtiles per wave (B-operand; scale pre-folded).
    h8 qf[2][2];
#pragma unroll
    for (int sub = 0; sub < 2; sub++) {
        const int qrow = q0 + (wv << 5) + (sub << 4) + col;
        const u16* qp = q + ((tok0 + qrow) << 9) + (h << 6) + (quad << 3);
#pragma unroll
        for (int kc = 0; kc < 2; kc++)
            qf[sub][kc] = *(const h8*)(qp + (kc << 5));
    }

    const f32x4 z4 = {0.f, 0.f, 0.f, 0.f};
    f32x4 o[2][4] = {{z4, z4, z4, z4}, {z4, z4, z4, z4}};
    float m_run[2] = {-1e30f, -1e30f}, l_run[2] = {0.f, 0.f};

    // staging map: 512 chunks/tile; wave wv issue j covers chunk ((j*4+wv)*64+lane)
    size_t kbz[2], vbz[2];
    int doff[2];
#pragma unroll
    for (int j = 0; j < 2; j++) {
        const int C = (((j << 2) + wv) << 6) + lane;
        const int sr = C >> 3, sp = (C & 7) ^ (sr & 7);
        kbz[j] = bhK + ((size_t)sr << 6) + (sp << 3);   // + jt*4096
        vbz[j] = bhK + ((size_t)sr << 11) + (sp << 3);  // + jt*64
        doff[j] = (((j << 2) + wv) << 9);
    }

    // prologue: K[0]->Kb0, V[0]->Vb0, K[1]->Kb1  (6 loads/wave outstanding)
#pragma unroll
    for (int j = 0; j < 2; j++) a16(&sm[doff[j]], kh + kbz[j]);
#pragma unroll
    for (int j = 0; j < 2; j++) a16(&sm[12288 + doff[j]], vth + vbz[j]);
#pragma unroll
    for (int j = 0; j < 2; j++) a16(&sm[4096 + doff[j]], kh + kbz[j] + 4096);

    int kcur = 0;  // u16 base of Kb[jt%3]
    for (int jt = 0; jt < 32; jt++) {
        // ONE barrier: retire own K[jt],V[jt] chunks (K[jt+1] in flight),
        // then sync -> all waves' chunks complete, all prior LDS reads done.
        if (jt < 31) {
            asm volatile("s_waitcnt vmcnt(2) lgkmcnt(0)\n\ts_barrier" ::: "memory");
        } else {
            asm volatile("s_waitcnt vmcnt(0) lgkmcnt(0)\n\ts_barrier" ::: "memory");
        }
        // issue V[jt+1] (other V buffer) and K[jt+2] (free K buffer).
        if (jt < 31) {
            const size_t vo = (size_t)(jt + 1) << 6;
            const int vb = 12288 + (((jt + 1) & 1) << 12);
#pragma unroll
            for (int j = 0; j < 2; j++) a16(&sm[vb + doff[j]], vth + vbz[j] + vo);
        }
        if (jt < 30) {
            const size_t ko = (size_t)(jt + 2) << 12;
            int kt = kcur + 8192; if (kt >= 12288) kt -= 12288;
#pragma unroll
            for (int j = 0; j < 2; j++) a16(&sm[kt + doff[j]], kh + kbz[j] + ko);
        }

        // ---- St[key][q] = K · Qᵀ (K frags feed both subtiles) ----
        f32x4 st0[4] = {z4, z4, z4, z4}, st1[4] = {z4, z4, z4, z4};
        __builtin_amdgcn_s_setprio(1);
#pragma unroll
        for (int kb = 0; kb < 4; kb++) {
            const int key = (kb << 4) + col;
            const int r64 = key << 6, k7 = key & 7;
#pragma unroll
            for (int kc = 0; kc < 2; kc++) {
                const int ofs = kcur + r64 + ((((kc << 2) + quad) ^ k7) << 3);
                h8 kf = *(const h8*)&sm[ofs];
                st0[kb] = __builtin_amdgcn_mfma_f32_16x16x32_f16(kf, qf[0][kc], st0[kb], 0, 0, 0);
                st1[kb] = __builtin_amdgcn_mfma_f32_16x16x32_f16(kf, qf[1][kc], st1[kb], 0, 0, 0);
            }
        }
        __builtin_amdgcn_s_setprio(0);

        // ---- online softmax per subtile (defer-rescale, __expf, pkrtz) ----
#pragma unroll
        for (int sub = 0; sub < 2; sub++) {
            f32x4* st = sub ? st1 : st0;
            const int prow = (wv << 5) + (sub << 4) + col;
            const int p64 = prow << 6, p7 = prow & 7;
            float mx = st[0][0];
#pragma unroll
            for (int kb = 0; kb < 4; kb++)
#pragma unroll
                for (int r = 0; r < 4; r++) mx = fmaxf(mx, st[kb][r]);
            mx = fmaxf(mx, __shfl_xor(mx, 16));
            mx = fmaxf(mx, __shfl_xor(mx, 32));
            if (__any(mx > m_run[sub] + 7.5f)) {
                const float mn  = fmaxf(m_run[sub], mx);
                const float alp = __expf(m_run[sub] - mn);
                m_run[sub] = mn;
                l_run[sub] *= alp;
                float aO[4];
#pragma unroll
                for (int r = 0; r < 4; r++) aO[r] = __shfl(alp, (quad << 2) + r);
#pragma unroll
                for (int db = 0; db < 4; db++) {
                    o[sub][db][0] *= aO[0]; o[sub][db][1] *= aO[1];
                    o[sub][db][2] *= aO[2]; o[sub][db][3] *= aO[3];
                }
            }
            float p[16];
            float rs = 0.0f;
#pragma unroll
            for (int kb = 0; kb < 4; kb++)
#pragma unroll
                for (int r = 0; r < 4; r++) {
                    float e = __expf(st[kb][r] - m_run[sub]);   // bounded by e^7.5
                    p[(kb << 2) + r] = e;
                    rs += e;
                }
            rs += __shfl_xor(rs, 16);
            rs += __shfl_xor(rs, 32);
            l_run[sub] += rs;
#pragma unroll
            for (int kb = 0; kb < 4; kb++) {
                uint2 w;
                w.x = pk2h(p[(kb << 2) + 0], p[(kb << 2) + 1]);
                w.y = pk2h(p[(kb << 2) + 2], p[(kb << 2) + 3]);
                const int c = (kb << 1) + (quad >> 1);
                *(uint2*)&sm[20480 + p64 + ((c ^ p7) << 3) + ((quad & 1) << 2)] = w;
            }
        }

        // wave-local fence: own P writes visible to own P reads. No barrier.
        asm volatile("s_waitcnt lgkmcnt(0)" ::: "memory");

        h8 pf[2][2];
#pragma unroll
        for (int sub = 0; sub < 2; sub++) {
            const int prow = (wv << 5) + (sub << 4) + col;
            const int p64 = prow << 6, p7 = prow & 7;
#pragma unroll
            for (int kc = 0; kc < 2; kc++)
                pf[sub][kc] = *(const h8*)&sm[20480 + p64 + ((((kc << 2) + quad) ^ p7) << 3)];
        }

        // ---- O += P · V (V frags feed both subtiles) ----
        const int vbase = 12288 + ((jt & 1) << 12);
        __builtin_amdgcn_s_setprio(1);
#pragma unroll
        for (int db = 0; db < 4; db++) {
            const int d = (db << 4) + col;
            const int v64 = vbase + (d << 6), d7 = d & 7;
#pragma unroll
            for (int kc = 0; kc < 2; kc++) {
                h8 vf = *(const h8*)&sm[v64 + ((((kc << 2) + quad) ^ d7) << 3)];
                o[0][db] = __builtin_amdgcn_mfma_f32_16x16x32_f16(pf[0][kc], vf, o[0][db], 0, 0, 0);
                o[1][db] = __builtin_amdgcn_mfma_f32_16x16x32_f16(pf[1][kc], vf, o[1][db], 0, 0, 0);
            }
        }
        __builtin_amdgcn_s_setprio(0);

        kcur = (kcur == 8192) ? 0 : kcur + 4096;
    }

    // ---- epilogue: O/l -> fp16 attended [tok][h*64+d] ----
#pragma unroll
    for (int sub = 0; sub < 2; sub++) {
        float linv[4];
#pragma unroll
        for (int r = 0; r < 4; r++) linv[r] = 1.0f / __shfl(l_run[sub], (quad << 2) + r);
#pragma unroll
        for (int r = 0; r < 4; r++) {
            const size_t rowo = ((tok0 + q0 + (wv << 5) + (sub << 4) + (quad << 2) + r) << 9)
                                + (h << 6) + col;
#pragma unroll
            for (int db = 0; db < 4; db++)
                ah[rowo + (db << 4)] = f2h(o[sub][db][r] * linv[r]);
        }
    }
}

// ---------------------------------------------------------------------------
extern "C" void kernel_launch(void* const* d_in, const int* in_sizes, int n_in,
                              void* d_out, int out_size, void* d_ws, size_t ws_size,
                              hipStream_t stream) {
    const float* x     = (const float*)d_in[0];
    const float* ln1_g = (const float*)d_in[1];
    const float* ln1_b = (const float*)d_in[2];
    const float* w_qkv = (const float*)d_in[3];
    const float* w_out = (const float*)d_in[4];
    const float* b_out = (const float*)d_in[5];
    const float* ln2_g = (const float*)d_in[6];
    const float* ln2_b = (const float*)d_in[7];
    const float* w1    = (const float*)d_in[8];
    const float* b1    = (const float*)d_in[9];
    const float* w2    = (const float*)d_in[10];
    const float* b2    = (const float*)d_in[11];
    float* out = (float*)d_out;

    u16* wqkvh = (u16*)d_ws;                       // [1536][512] fp16
    u16* wouth = wqkvh + 1536 * 512;               // [512][512]
    u16* w1h   = wouth + 512 * 512;                // [1024][512]
    u16* w2h   = w1h + 1024 * 512;                 // [512][1024]
    u16* hbuf  = w2h + 512 * 1024;                 // [8192][512] fp16: h/att/mid
    float* qbuf = (float*)(hbuf + (size_t)TOKENS * 512);   // region: q fp16 / x2 fp16
    u16* qh16   = (u16*)qbuf;                              // [8192][512] fp16 (q*0.125)
    u16* x2h    = (u16*)qbuf;                              // [8192][512] fp16 (after attn)
    u16* kh  = (u16*)(qbuf + (size_t)TOKENS * 512);        // [32][2048][64] fp16
    u16* vth = kh + (size_t)32 * 131072;                   // [32][64][2048] fp16
    u16* gh  = kh;                                         // [8192][1024] fp16 (aliases k+v)

    prep_k<<<2560, 256, 0, stream>>>(w_qkv, w_out, w1, w2, wqkvh, wouth, w1h, w2h,
                                     x, ln1_g, ln1_b, hbuf);
    sgemm_k<0><<<dim3(12, 64), 256, 0, stream>>>(hbuf, wqkvh, nullptr, nullptr,
                                                 (float*)qh16, kh, vth, TOKENS, 1536, 512);
    attn_k<<<dim3(16, 32), 256, 0, stream>>>(qh16, kh, vth, hbuf);
    sgemm_k<1><<<dim3(4, 64), 256, 0, stream>>>(hbuf, wouth, b_out, x,
                                                nullptr, x2h, nullptr, TOKENS, 512, 512);
    ln_k<<<TOKENS / 4, 256, 0, stream>>>(x2h, ln2_g, ln2_b, hbuf);
    sgemm_k<2><<<dim3(8, 64), 256, 0, stream>>>(hbuf, w1h, b1, nullptr,
                                                nullptr, gh, nullptr, TOKENS, 1024, 512);
    sgemm_k<3><<<dim3(4, 64), 256, 0, stream>>>(gh, w2h, b2, (const float*)x2h,
                                                out, nullptr, nullptr, TOKENS, 512, 1024);
}